// Round 11
// baseline (348.172 us; speedup 1.0000x reference)
//
#include <hip/hip_runtime.h>
#include <math.h>

static constexpr int Bb  = 16;
static constexpr int Nn  = 512;
static constexpr int Dd  = 512;
static constexpr int Hh  = 8;
static constexpr int HDd = 64;
static constexpr int UEe = 6;
static constexpr int DFFf= 2048;

typedef __attribute__((ext_vector_type(8))) short short8v;
typedef __attribute__((ext_vector_type(4))) float f32x4;

__device__ __forceinline__ short f2bf(float f) {
  unsigned u = __float_as_uint(f);
  unsigned r = (u + 0x7fffu + ((u >> 16) & 1u)) >> 16;
  return (short)r;
}
__device__ __forceinline__ float bf2f(short h) {
  return __uint_as_float(((unsigned)(unsigned short)h) << 16);
}
__device__ __forceinline__ void split2(float v, short& hi, short& lo) {
  hi = f2bf(v);
  lo = f2bf(v - bf2f(hi));
}

// ---------------- block reduction helpers (256 threads, 4 waves) ----------------

__device__ __forceinline__ float2 block_sum2(float a, float b, float* sb) {
  #pragma unroll
  for (int o = 32; o; o >>= 1) { a += __shfl_down(a, o); b += __shfl_down(b, o); }
  const int lane = threadIdx.x & 63, wid = threadIdx.x >> 6;
  if (lane == 0) { sb[wid] = a; sb[4 + wid] = b; }
  __syncthreads();
  float ra = sb[0] + sb[1] + sb[2] + sb[3];
  float rb = sb[4] + sb[5] + sb[6] + sb[7];
  __syncthreads();
  return make_float2(ra, rb);
}

__device__ __forceinline__ float block_sum1(float a, float* sb) {
  #pragma unroll
  for (int o = 32; o; o >>= 1) a += __shfl_down(a, o);
  const int lane = threadIdx.x & 63, wid = threadIdx.x >> 6;
  if (lane == 0) sb[wid] = a;
  __syncthreads();
  float ra = sb[0] + sb[1] + sb[2] + sb[3];
  __syncthreads();
  return ra;
}

// ---------------- LayerNorm on x -> xn (split bf16 hi/lo) ----------------

__global__ __launch_bounds__(256) void ln1_kernel(
    const float* __restrict__ x, const float* __restrict__ w,
    const float* __restrict__ b, short* __restrict__ oh, short* __restrict__ ol) {
  __shared__ float sb[8];
  const size_t row = blockIdx.x;
  const int t = threadIdx.x;
  const float* xr = x + row * Dd;
  float2 xv = *(const float2*)(xr + 2 * t);
  float2 r = block_sum2(xv.x + xv.y, xv.x * xv.x + xv.y * xv.y, sb);
  const float mu = r.x * (1.f / Dd);
  const float var = r.y * (1.f / Dd) - mu * mu;
  const float rstd = rsqrtf(var + 1e-5f);
  float2 wv = *(const float2*)(w + 2 * t);
  float2 bv = *(const float2*)(b + 2 * t);
  float v0 = (xv.x - mu) * rstd * wv.x + bv.x;
  float v1 = (xv.y - mu) * rstd * wv.y + bv.y;
  short2 h2, l2;
  split2(v0, h2.x, l2.x);
  split2(v1, h2.y, l2.y);
  *(short2*)(oh + row * Dd + 2 * t) = h2;
  *(short2*)(ol + row * Dd + 2 * t) = l2;
}

// ------- LN2(attn_out)+residual -> h (f32) ; RMSNorm(h) -> zbf (bf16) -------

__global__ __launch_bounds__(256) void hz_kernel(
    const float* __restrict__ ao, const float* __restrict__ xres,
    const float* __restrict__ w, const float* __restrict__ b,
    const float* __restrict__ rw,
    float* __restrict__ h, short* __restrict__ zbf) {
  __shared__ float sb[8];
  const size_t row = blockIdx.x;
  const int t = threadIdx.x;
  float2 av = *(const float2*)(ao + row * Dd + 2 * t);
  float2 r = block_sum2(av.x + av.y, av.x * av.x + av.y * av.y, sb);
  const float mu = r.x * (1.f / Dd);
  const float var = r.y * (1.f / Dd) - mu * mu;
  const float rstd = rsqrtf(var + 1e-5f);
  float2 wv = *(const float2*)(w + 2 * t);
  float2 bv = *(const float2*)(b + 2 * t);
  float2 xv = *(const float2*)(xres + row * Dd + 2 * t);
  float2 hv;
  hv.x = (av.x - mu) * rstd * wv.x + bv.x + xv.x;
  hv.y = (av.y - mu) * rstd * wv.y + bv.y + xv.y;
  *(float2*)(h + row * Dd + 2 * t) = hv;
  float ms = block_sum1(hv.x * hv.x + hv.y * hv.y, sb) * (1.f / Dd);
  const float rr = rsqrtf(ms + 1.1920929e-07f);
  float2 rwv = *(const float2*)(rw + 2 * t);
  short2 zv;
  zv.x = f2bf(hv.x * rr * rwv.x);
  zv.y = f2bf(hv.y * rr * rwv.y);
  *(short2*)(zbf + row * Dd + 2 * t) = zv;
}

// ---------------- f32 -> bf16 converts ----------------

__global__ __launch_bounds__(256) void cvt_kernel(
    const float* __restrict__ in, short* __restrict__ out, int n4) {
  int i = blockIdx.x * 256 + threadIdx.x;
  if (i < n4) {
    float4 v = ((const float4*)in)[i];
    short4 o;
    o.x = f2bf(v.x); o.y = f2bf(v.y); o.z = f2bf(v.z); o.w = f2bf(v.w);
    ((short4*)out)[i] = o;
  }
}

__global__ __launch_bounds__(256) void cvt2_kernel(
    const float* __restrict__ in, short* __restrict__ hi,
    short* __restrict__ lo, int n4) {
  int i = blockIdx.x * 256 + threadIdx.x;
  if (i < n4) {
    float4 v = ((const float4*)in)[i];
    short4 h, l;
    split2(v.x, h.x, l.x); split2(v.y, h.y, l.y);
    split2(v.z, h.z, l.z); split2(v.w, h.w, l.w);
    ((short4*)hi)[i] = h;
    ((short4*)lo)[i] = l;
  }
}

// -------- V transpose: v[8192][512] bf16 -> vT[b][h][hd(64)][n(512)] bf16 --------

__global__ __launch_bounds__(256) void vt_kernel(
    const short* __restrict__ v, short* __restrict__ vT) {
  __shared__ short Lt[64][72];
  const int z = blockIdx.y, b = z >> 3, hh = z & 7;
  const int n0 = blockIdx.x * 64;
  const int tid = threadIdx.x;
  #pragma unroll
  for (int it = 0; it < 2; ++it) {
    int id = tid + it * 256;
    int r = id >> 3, c8 = id & 7;
    *(short8v*)&Lt[r][c8 * 8] =
        *(const short8v*)(v + ((size_t)(b * Nn + n0 + r)) * Dd + hh * HDd + c8 * 8);
  }
  __syncthreads();
  #pragma unroll
  for (int it = 0; it < 2; ++it) {
    int id = tid + it * 256;
    int c = id >> 3, r8 = id & 7;
    short8v g;
    #pragma unroll
    for (int k = 0; k < 8; ++k) g[k] = Lt[r8 * 8 + k][c];
    *(short8v*)(vT + ((size_t)z * HDd + c) * Nn + n0 + r8 * 8) = g;
  }
}

// ------ merged QKV 3-term split-bf16 NT GEMM ------

__global__ __launch_bounds__(256) void mfma_qkv3_kernel(
    const short* __restrict__ Ah, const short* __restrict__ Al,
    const short* __restrict__ Wh, const short* __restrict__ Wl,
    short* __restrict__ qh_, short* __restrict__ ql_,
    short* __restrict__ kh_, short* __restrict__ kl_,
    short* __restrict__ vh_) {
  constexpr int MREP = 4, NREP = 2;
  __shared__ short Ash[128][40], Asl[128][40], Bsh[64][40], Bsl[64][40];
  const int tid = threadIdx.x;
  const int wave = tid >> 6, lane = tid & 63;
  const int wr = wave >> 1, wc = wave & 1;
  const int lrow = lane & 15, kblk = lane >> 4;
  const size_t bm = (size_t)blockIdx.y * 128, bn = (size_t)blockIdx.x * 64;
  f32x4 acc[MREP][NREP] = {};
  for (int k0 = 0; k0 < Dd; k0 += 32) {
    __syncthreads();
    #pragma unroll
    for (int it = 0; it < 2; ++it) {
      int id = tid + it * 256;
      int r = id >> 2, kq = id & 3;
      const size_t go = (bm + r) * Dd + k0 + kq * 8;
      *(short8v*)&Ash[r][kq * 8] = *(const short8v*)(Ah + go);
      *(short8v*)&Asl[r][kq * 8] = *(const short8v*)(Al + go);
    }
    {
      int r = tid >> 2, kq = tid & 3;
      const size_t go = (bn + r) * Dd + k0 + kq * 8;
      *(short8v*)&Bsh[r][kq * 8] = *(const short8v*)(Wh + go);
      *(short8v*)&Bsl[r][kq * 8] = *(const short8v*)(Wl + go);
    }
    __syncthreads();
    short8v afh[MREP], afl[MREP], bfh[NREP], bfl[NREP];
    #pragma unroll
    for (int i = 0; i < MREP; ++i) {
      afh[i] = *(const short8v*)&Ash[wr * 64 + i * 16 + lrow][kblk * 8];
      afl[i] = *(const short8v*)&Asl[wr * 64 + i * 16 + lrow][kblk * 8];
    }
    #pragma unroll
    for (int j = 0; j < NREP; ++j) {
      bfh[j] = *(const short8v*)&Bsh[wc * 32 + j * 16 + lrow][kblk * 8];
      bfl[j] = *(const short8v*)&Bsl[wc * 32 + j * 16 + lrow][kblk * 8];
    }
    #pragma unroll
    for (int i = 0; i < MREP; ++i)
      #pragma unroll
      for (int j = 0; j < NREP; ++j) {
        acc[i][j] = __builtin_amdgcn_mfma_f32_16x16x32_bf16(afh[i], bfh[j], acc[i][j], 0, 0, 0);
        acc[i][j] = __builtin_amdgcn_mfma_f32_16x16x32_bf16(afl[i], bfh[j], acc[i][j], 0, 0, 0);
        acc[i][j] = __builtin_amdgcn_mfma_f32_16x16x32_bf16(afh[i], bfl[j], acc[i][j], 0, 0, 0);
      }
  }
  const int seg = (int)(bn >> 9);  // uniform per block
  short* dsth = seg == 0 ? qh_ : (seg == 1 ? kh_ : vh_);
  short* dstl = seg == 0 ? ql_ : kl_;
  #pragma unroll
  for (int i = 0; i < MREP; ++i) {
    #pragma unroll
    for (int j = 0; j < NREP; ++j) {
      const size_t gcol = (bn & 511) + wc * 32 + j * 16 + lrow;
      #pragma unroll
      for (int reg = 0; reg < 4; ++reg) {
        const size_t grow = bm + wr * 64 + i * 16 + kblk * 4 + reg;
        float vv = acc[i][j][reg];
        if (seg < 2) {
          short hh_, ll_;
          split2(vv, hh_, ll_);
          dsth[grow * Dd + gcol] = hh_;
          dstl[grow * Dd + gcol] = ll_;
        } else {
          dsth[grow * Dd + gcol] = f2bf(vv);
        }
      }
    }
  }
}

// ------ 3-term split-bf16 NT GEMM (out-proj): C = (Ah+Al)@(Wh+Wl)^T ------

template <int EPI>
__global__ __launch_bounds__(256) void mfma_nt3_kernel(
    const short* __restrict__ Ah, const short* __restrict__ Al,
    const short* __restrict__ Wh, const short* __restrict__ Wl,
    void* __restrict__ C1, void* __restrict__ C2,
    const float* __restrict__ bias, int Nc, int K) {
  constexpr int BM = 128, BN = 64;
  constexpr int MREP = 4, NREP = 2;
  __shared__ short Ash[BM][40], Asl[BM][40], Bsh[BN][40], Bsl[BN][40];
  const int tid = threadIdx.x;
  const int wave = tid >> 6, lane = tid & 63;
  const int wr = wave >> 1, wc = wave & 1;
  const int lrow = lane & 15, kblk = lane >> 4;
  const size_t bm = (size_t)blockIdx.y * BM, bn = (size_t)blockIdx.x * BN;
  f32x4 acc[MREP][NREP] = {};
  for (int k0 = 0; k0 < K; k0 += 32) {
    __syncthreads();
    #pragma unroll
    for (int it = 0; it < 2; ++it) {
      int id = tid + it * 256;
      int r = id >> 2, kq = id & 3;
      const size_t go = (bm + r) * K + k0 + kq * 8;
      *(short8v*)&Ash[r][kq * 8] = *(const short8v*)(Ah + go);
      *(short8v*)&Asl[r][kq * 8] = *(const short8v*)(Al + go);
    }
    {
      int r = tid >> 2, kq = tid & 3;
      const size_t go = (bn + r) * K + k0 + kq * 8;
      *(short8v*)&Bsh[r][kq * 8] = *(const short8v*)(Wh + go);
      *(short8v*)&Bsl[r][kq * 8] = *(const short8v*)(Wl + go);
    }
    __syncthreads();
    short8v afh[MREP], afl[MREP], bfh[NREP], bfl[NREP];
    #pragma unroll
    for (int i = 0; i < MREP; ++i) {
      afh[i] = *(const short8v*)&Ash[wr * 64 + i * 16 + lrow][kblk * 8];
      afl[i] = *(const short8v*)&Asl[wr * 64 + i * 16 + lrow][kblk * 8];
    }
    #pragma unroll
    for (int j = 0; j < NREP; ++j) {
      bfh[j] = *(const short8v*)&Bsh[wc * 32 + j * 16 + lrow][kblk * 8];
      bfl[j] = *(const short8v*)&Bsl[wc * 32 + j * 16 + lrow][kblk * 8];
    }
    #pragma unroll
    for (int i = 0; i < MREP; ++i)
      #pragma unroll
      for (int j = 0; j < NREP; ++j) {
        acc[i][j] = __builtin_amdgcn_mfma_f32_16x16x32_bf16(afh[i], bfh[j], acc[i][j], 0, 0, 0);
        acc[i][j] = __builtin_amdgcn_mfma_f32_16x16x32_bf16(afl[i], bfh[j], acc[i][j], 0, 0, 0);
        acc[i][j] = __builtin_amdgcn_mfma_f32_16x16x32_bf16(afh[i], bfl[j], acc[i][j], 0, 0, 0);
      }
  }
  #pragma unroll
  for (int i = 0; i < MREP; ++i) {
    #pragma unroll
    for (int j = 0; j < NREP; ++j) {
      const size_t gcol = bn + wc * 32 + j * 16 + lrow;
      float bb = 0.f;
      if constexpr (EPI == 1) bb = bias[gcol];
      #pragma unroll
      for (int reg = 0; reg < 4; ++reg) {
        const size_t grow = bm + wr * 64 + i * 16 + kblk * 4 + reg;
        float vv = acc[i][j][reg] + bb;
        if constexpr (EPI == 0) {
          short hh_, ll_;
          split2(vv, hh_, ll_);
          ((short*)C1)[grow * Nc + gcol] = hh_;
          ((short*)C2)[grow * Nc + gcol] = ll_;
        } else if constexpr (EPI == 1) {
          ((float*)C1)[grow * Nc + gcol] = vv;
        } else {
          ((short*)C1)[grow * Nc + gcol] = f2bf(vv);
        }
      }
    }
  }
}

// -------- fattn: fused scores (3-term) + u-bias + softmax + P write + P@V --------
// grid (Nn/32 = 16 row-tiles, B*H = 128). 256 threads, 2x2 waves.
// Per-thread score layout: thread (lr = tid>>3, sub = tid&7) owns row row0+lr,
// float4 s[t] at cols 4*(sub + 8*t), t = 0..15. j-tile jt fills t = 2jt, 2jt+1.
// LDS union: phase A {Qs 9.2K, Ks 18.4K, Sls 8.7K} / phase C {Ps 33.3K, Bs 17.4K}.

__global__ __launch_bounds__(256) void fattn_kernel(
    const short* __restrict__ qh, const short* __restrict__ ql,
    const short* __restrict__ kh, const short* __restrict__ kl,
    const short* __restrict__ vT, float* __restrict__ P,
    const float* __restrict__ u, const float* __restrict__ u_w,
    const float* __restrict__ u_b,
    short* __restrict__ ctxh, short* __restrict__ ctxl) {
  __shared__ __align__(16) char smem[50688];
  short (*Qsh)[72] = (short(*)[72])(smem + 0);
  short (*Qsl)[72] = (short(*)[72])(smem + 4608);
  short (*Ksh)[72] = (short(*)[72])(smem + 9216);
  short (*Ksl)[72] = (short(*)[72])(smem + 18432);
  float (*Sls)[68] = (float(*)[68])(smem + 27648);   // ends 36352
  short (*Ps)[520] = (short(*)[520])(smem + 0);      // phase C, ends 33280
  short (*Bs)[136] = (short(*)[136])(smem + 33280);  // phase C, ends 50688
  const int z = blockIdx.y, b = z >> 3, h = z & 7;
  const int row0 = blockIdx.x * 32;
  const int tid = threadIdx.x;
  const int lr = tid >> 3, sub = tid & 7;
  const int wave = tid >> 6, lane = tid & 63;
  const int wr = wave >> 1, wc = wave & 1;
  const int lrow = lane & 15, kblk = lane >> 4;

  // stage Q (32 rows x 64 k) hi/lo, once
  {
    const size_t gq = ((size_t)(b * Nn) + row0 + lr) * Dd + h * HDd + sub * 8;
    *(short8v*)&Qsh[lr][sub * 8] = *(const short8v*)(qh + gq);
    *(short8v*)&Qsl[lr][sub * 8] = *(const short8v*)(ql + gq);
  }
  float uw[UEe];
  #pragma unroll
  for (int c = 0; c < UEe; ++c) uw[c] = u_w[h * UEe + c];
  const float ubh = u_b[h];
  const float* ub_ = u + (size_t)b * UEe * Nn * Nn;

  float4 s[16];
  #pragma unroll
  for (int jt = 0; jt < 8; ++jt) {
    __syncthreads();  // Q visible (1st iter); prev pickup Sls-reads + MFMA Ks-reads done
    #pragma unroll
    for (int it = 0; it < 2; ++it) {
      int id = tid + it * 256;
      int r = id >> 3, kq = id & 7;
      const size_t gk = ((size_t)(b * Nn) + jt * 64 + r) * Dd + h * HDd + kq * 8;
      *(short8v*)&Ksh[r][kq * 8] = *(const short8v*)(kh + gk);
      *(short8v*)&Ksl[r][kq * 8] = *(const short8v*)(kl + gk);
    }
    __syncthreads();
    f32x4 acc[2] = {};
    #pragma unroll
    for (int ks = 0; ks < 2; ++ks) {
      short8v afh = *(const short8v*)&Qsh[wr * 16 + lrow][ks * 32 + kblk * 8];
      short8v afl = *(const short8v*)&Qsl[wr * 16 + lrow][ks * 32 + kblk * 8];
      #pragma unroll
      for (int j = 0; j < 2; ++j) {
        short8v bfh = *(const short8v*)&Ksh[wc * 32 + j * 16 + lrow][ks * 32 + kblk * 8];
        short8v bfl = *(const short8v*)&Ksl[wc * 32 + j * 16 + lrow][ks * 32 + kblk * 8];
        acc[j] = __builtin_amdgcn_mfma_f32_16x16x32_bf16(afh, bfh, acc[j], 0, 0, 0);
        acc[j] = __builtin_amdgcn_mfma_f32_16x16x32_bf16(afl, bfh, acc[j], 0, 0, 0);
        acc[j] = __builtin_amdgcn_mfma_f32_16x16x32_bf16(afh, bfl, acc[j], 0, 0, 0);
      }
    }
    // dump fragments -> Sls (scale by 8)
    #pragma unroll
    for (int j = 0; j < 2; ++j)
      #pragma unroll
      for (int reg = 0; reg < 4; ++reg)
        Sls[wr * 16 + kblk * 4 + reg][wc * 32 + j * 16 + lrow] = 8.f * acc[j][reg];
    __syncthreads();
    // pickup + u-bias into register layout
    #pragma unroll
    for (int dt = 0; dt < 2; ++dt) {
      const int t = jt * 2 + dt;
      float4 v = *(const float4*)&Sls[lr][dt * 32 + sub * 4];
      const size_t goff = (size_t)(row0 + lr) * Nn + 4 * (sub + 8 * t);
      v.x += ubh; v.y += ubh; v.z += ubh; v.w += ubh;
      #pragma unroll
      for (int c = 0; c < UEe; ++c) {
        float4 uv = *(const float4*)(ub_ + (size_t)c * Nn * Nn + goff);
        v.x = fmaf(uw[c], uv.x, v.x);
        v.y = fmaf(uw[c], uv.y, v.y);
        v.z = fmaf(uw[c], uv.z, v.z);
        v.w = fmaf(uw[c], uv.w, v.w);
      }
      s[t] = v;
    }
  }
  __syncthreads();  // all phase-A LDS reads done before Ps overlays

  // ---- softmax over s[16] (8-thread row groups, shfl over sub) ----
  float m = -1e30f;
  #pragma unroll
  for (int q = 0; q < 16; ++q)
    m = fmaxf(m, fmaxf(fmaxf(s[q].x, s[q].y), fmaxf(s[q].z, s[q].w)));
  m = fmaxf(m, __shfl_xor(m, 1));
  m = fmaxf(m, __shfl_xor(m, 2));
  m = fmaxf(m, __shfl_xor(m, 4));
  float sum = 0.f;
  #pragma unroll
  for (int q = 0; q < 16; ++q) {
    s[q].x = __expf(s[q].x - m); s[q].y = __expf(s[q].y - m);
    s[q].z = __expf(s[q].z - m); s[q].w = __expf(s[q].w - m);
    sum += (s[q].x + s[q].y) + (s[q].z + s[q].w);
  }
  sum += __shfl_xor(sum, 1);
  sum += __shfl_xor(sum, 2);
  sum += __shfl_xor(sum, 4);
  const float rr = 1.f / sum;
  // ---- P write (f32) + Ps pack (bf16) ----
  float* Pp = P + (size_t)z * Nn * Nn + (size_t)(row0 + lr) * Nn;
  #pragma unroll
  for (int q = 0; q < 16; ++q) {
    s[q].x *= rr; s[q].y *= rr; s[q].z *= rr; s[q].w *= rr;
    const int col = 4 * (sub + 8 * q);
    *(float4*)(Pp + col) = s[q];
    short4 pk;
    pk.x = f2bf(s[q].x); pk.y = f2bf(s[q].y);
    pk.z = f2bf(s[q].z); pk.w = f2bf(s[q].w);
    *(short4*)&Ps[lr][col] = pk;
  }
  // ---- PV MFMA: ctx_tile[32][64] = P_tile[32][512] @ V[512][64] ----
  f32x4 acc0 = {}, acc1 = {};
  for (int kc = 0; kc < 4; ++kc) {
    __syncthreads();  // (1st iter: Ps writes visible; later: prev MFMA Bs reads done)
    #pragma unroll
    for (int it = 0; it < 4; ++it) {
      int id = tid + it * 256;
      int rrow = id >> 4, k8 = id & 15;
      *(short8v*)&Bs[rrow][k8 * 8] =
          *(const short8v*)(vT + ((size_t)z * HDd + rrow) * Nn + kc * 128 + k8 * 8);
    }
    __syncthreads();
    #pragma unroll
    for (int ks = 0; ks < 4; ++ks) {
      short8v af = *(const short8v*)&Ps[wr * 16 + lrow][kc * 128 + ks * 32 + kblk * 8];
      short8v b0 = *(const short8v*)&Bs[wc * 32 + lrow][ks * 32 + kblk * 8];
      short8v b1 = *(const short8v*)&Bs[wc * 32 + 16 + lrow][ks * 32 + kblk * 8];
      acc0 = __builtin_amdgcn_mfma_f32_16x16x32_bf16(af, b0, acc0, 0, 0, 0);
      acc1 = __builtin_amdgcn_mfma_f32_16x16x32_bf16(af, b1, acc1, 0, 0, 0);
    }
  }
  const size_t outbase =
      ((size_t)(b * Nn + row0 + wr * 16 + kblk * 4)) * Dd + h * HDd + wc * 32 + lrow;
  #pragma unroll
  for (int reg = 0; reg < 4; ++reg) {
    short h0, l0, h1, l1;
    split2(acc0[reg], h0, l0);
    split2(acc1[reg], h1, l1);
    ctxh[outbase + (size_t)reg * Dd] = h0;
    ctxl[outbase + (size_t)reg * Dd] = l0;
    ctxh[outbase + (size_t)reg * Dd + 16] = h1;
    ctxl[outbase + (size_t)reg * Dd + 16] = l1;
  }
}

// ---------------- bf16 MFMA NT GEMM (FFN) ----------------

template <int BM, int BN, int EPI>
__global__ __launch_bounds__(256) void mfma_nt_kernel(
    const short* __restrict__ Ag, const short* __restrict__ Wg,
    void* __restrict__ Cv, const float* __restrict__ bias,
    const float* __restrict__ res, int Nc, int K) {
  constexpr int MREP = BM / 32, NREP = BN / 32;
  __shared__ short As[BM][72];
  __shared__ short Bs[BN][72];
  const int tid = threadIdx.x;
  const int wave = tid >> 6, lane = tid & 63;
  const int wr = wave >> 1, wc = wave & 1;
  const int lrow = lane & 15, kblk = lane >> 4;
  const size_t bm = (size_t)blockIdx.y * BM, bn = (size_t)blockIdx.x * BN;
  f32x4 acc[MREP][NREP] = {};
  for (int k0 = 0; k0 < K; k0 += 32) {
    __syncthreads();
    #pragma unroll
    for (int it = 0; it < BM / 64; ++it) {
      int id = tid + it * 256;
      int r = id >> 2, kq = id & 3;
      *(short8v*)&As[r][kq * 8] = *(const short8v*)(Ag + (bm + r) * K + k0 + kq * 8);
    }
    #pragma unroll
    for (int it = 0; it < BN / 64; ++it) {
      int id = tid + it * 256;
      int r = id >> 2, kq = id & 3;
      *(short8v*)&Bs[r][kq * 8] = *(const short8v*)(Wg + (bn + r) * K + k0 + kq * 8);
    }
    __syncthreads();
    short8v af[MREP], bf[NREP];
    #pragma unroll
    for (int i = 0; i < MREP; ++i)
      af[i] = *(const short8v*)&As[wr * (BM / 2) + i * 16 + lrow][kblk * 8];
    #pragma unroll
    for (int j = 0; j < NREP; ++j)
      bf[j] = *(const short8v*)&Bs[wc * (BN / 2) + j * 16 + lrow][kblk * 8];
    #pragma unroll
    for (int i = 0; i < MREP; ++i)
      #pragma unroll
      for (int j = 0; j < NREP; ++j)
        acc[i][j] = __builtin_amdgcn_mfma_f32_16x16x32_bf16(af[i], bf[j], acc[i][j], 0, 0, 0);
  }
  #pragma unroll
  for (int i = 0; i < MREP; ++i) {
    #pragma unroll
    for (int j = 0; j < NREP; ++j) {
      const size_t gcol = bn + wc * (BN / 2) + j * 16 + lrow;
      const float bb = bias[gcol];
      #pragma unroll
      for (int reg = 0; reg < 4; ++reg) {
        const size_t grow = bm + wr * (BM / 2) + i * 16 + kblk * 4 + reg;
        float vv = acc[i][j][reg] + bb;
        if constexpr (EPI == 0) {
          vv = vv / (1.f + __expf(-vv));
          ((short*)Cv)[grow * Nc + gcol] = f2bf(vv);
        } else {
          ((float*)Cv)[grow * Nc + gcol] = vv + res[grow * Nc + gcol];
        }
      }
    }
  }
}

// ---------------- host launch ----------------

extern "C" void kernel_launch(void* const* d_in, const int* in_sizes, int n_in,
                              void* d_out, int out_size, void* d_ws, size_t ws_size,
                              hipStream_t stream) {
  const float* x     = (const float*)d_in[0];
  const float* u     = (const float*)d_in[1];
  const float* ln1_w = (const float*)d_in[2];
  const float* ln1_b = (const float*)d_in[3];
  const float* ln2_w = (const float*)d_in[4];
  const float* ln2_b = (const float*)d_in[5];
  const float* wq    = (const float*)d_in[6];
  const float* wk    = (const float*)d_in[7];
  const float* wv    = (const float*)d_in[8];
  const float* wo    = (const float*)d_in[9];
  const float* bo    = (const float*)d_in[10];
  const float* u_w   = (const float*)d_in[11];
  const float* u_b   = (const float*)d_in[12];
  const float* rms_w = (const float*)d_in[13];
  const float* w1    = (const float*)d_in[14];
  const float* b1    = (const float*)d_in[15];
  const float* w2    = (const float*)d_in[16];
  const float* b2    = (const float*)d_in[17];

  float* out   = (float*)d_out;
  float* attnW = out + (size_t)Bb * Nn * Dd;  // second output: [B,H,N,N]

  const size_t SB = (size_t)Bb * Nn * Dd * 2;  // 8 MB
  char* wsb = (char*)d_ws;
  // slot map (8 MB each):
  // 0: xnh -> vTh -> zbf     | 1: xnl -> ctxh -> h1bf[0:8]
  // 2: qh  -> aout[0:8]      | 3: ql -> aout[8:16]   (h1bf[8:24] after hz)
  // 4: kh  -> h1bf[24:32]    | 5: kl -> hbuf[0:8]
  // 6: vh  -> ctxl -> hbuf[8:16]
  short* xnh  = (short*)(wsb + 0 * SB);
  short* xnl  = (short*)(wsb + 1 * SB);
  short* qh   = (short*)(wsb + 2 * SB);
  short* ql   = (short*)(wsb + 3 * SB);
  short* kh   = (short*)(wsb + 4 * SB);
  short* kl   = (short*)(wsb + 5 * SB);
  short* vh   = (short*)(wsb + 6 * SB);
  short* vTh  = (short*)(wsb + 0 * SB);
  short* ctxh = (short*)(wsb + 1 * SB);
  short* ctxl = (short*)(wsb + 6 * SB);
  float* aout = (float*)(wsb + 2 * SB);
  float* hbuf = (float*)(wsb + 5 * SB);
  short* zbf  = (short*)(wsb + 0 * SB);
  short* h1bf = (short*)(wsb + 1 * SB);  // 32 MB: slots 1-4
  const size_t WTBYTES = 8 * (size_t)Dd * Dd * 2 + 2 * (size_t)DFFf * Dd * 2;
  const size_t wt = (ws_size - WTBYTES) & ~(size_t)255;
  short* wAh = (short*)(wsb + wt);
  short* wAl = wAh + 3 * (size_t)Dd * Dd;
  short* woh = wAl + 3 * (size_t)Dd * Dd;
  short* wol = woh + (size_t)Dd * Dd;
  short* w1h = wol + (size_t)Dd * Dd;
  short* w2h = w1h + (size_t)DFFf * Dd;

  const int MR = Bb * Nn;  // 8192 rows

  // 0. weight converts
  cvt2_kernel<<<256, 256, 0, stream>>>(wq, wAh, wAl, Dd * Dd / 4);
  cvt2_kernel<<<256, 256, 0, stream>>>(wk, wAh + (size_t)Dd * Dd, wAl + (size_t)Dd * Dd, Dd * Dd / 4);
  cvt2_kernel<<<256, 256, 0, stream>>>(wv, wAh + 2 * (size_t)Dd * Dd, wAl + 2 * (size_t)Dd * Dd, Dd * Dd / 4);
  cvt2_kernel<<<256, 256, 0, stream>>>(wo, woh, wol, Dd * Dd / 4);
  cvt_kernel<<<1024, 256, 0, stream>>>(w1, w1h, DFFf * Dd / 4);
  cvt_kernel<<<1024, 256, 0, stream>>>(w2, w2h, DFFf * Dd / 4);

  // 1. LayerNorm1 -> split bf16
  ln1_kernel<<<MR, 256, 0, stream>>>(x, ln1_w, ln1_b, xnh, xnl);

  // 2. merged Q,K,V projection (3-term split MFMA)
  dim3 gQKV(3 * Dd / 64, MR / 128);
  mfma_qkv3_kernel<<<gQKV,256,0,stream>>>(xnh, xnl, wAh, wAl, qh, ql, kh, kl, vh);

  // 3. V transpose per head
  dim3 gVt(Nn / 64, Bb * Hh);
  vt_kernel<<<gVt, 256, 0, stream>>>(vh, vTh);

  // 4. fused scores + u-bias + softmax + P + P@V
  dim3 gFa(Nn / 32, Bb * Hh);
  fattn_kernel<<<gFa, 256, 0, stream>>>(qh, ql, kh, kl, vTh, attnW,
                                        u, u_w, u_b, ctxh, ctxl);

  // 5. attn_out = ctx @ wo^T + bo (3-term, f32 out)
  dim3 gProj(Dd / 64, MR / 128);
  mfma_nt3_kernel<1><<<gProj,256,0,stream>>>(ctxh, ctxl, woh, wol, aout, nullptr, bo, Dd, Dd);

  // 6. h = LN2(attn_out) + x ; zbf = bf16(RMSNorm(h))
  hz_kernel<<<MR, 256, 0, stream>>>(aout, x, ln2_w, ln2_b, rms_w, hbuf, zbf);

  // 7/8. FFN bf16 MFMA, single pass (h1bf = 32 MB, slots 1-4)
  dim3 gF1(DFFf / 128, MR / 128);
  mfma_nt_kernel<128,128,0><<<gF1,256,0,stream>>>(
      zbf, w1h, h1bf, b1, nullptr, DFFf, Dd);
  dim3 gF2(Dd / 128, MR / 64);
  mfma_nt_kernel<64,128,1><<<gF2,256,0,stream>>>(
      h1bf, w2h, out, b2, hbuf, Dd, DFFf);
}

// Round 13
// 338.029 us; speedup vs baseline: 1.0300x; 1.0300x over previous
//
#include <hip/hip_runtime.h>
#include <math.h>

static constexpr int Bb  = 16;
static constexpr int Nn  = 512;
static constexpr int Dd  = 512;
static constexpr int Hh  = 8;
static constexpr int HDd = 64;
static constexpr int UEe = 6;
static constexpr int DFFf= 2048;

typedef __attribute__((ext_vector_type(8))) short short8v;
typedef __attribute__((ext_vector_type(4))) float f32x4;

__device__ __forceinline__ short f2bf(float f) {
  unsigned u = __float_as_uint(f);
  unsigned r = (u + 0x7fffu + ((u >> 16) & 1u)) >> 16;
  return (short)r;
}
__device__ __forceinline__ float bf2f(short h) {
  return __uint_as_float(((unsigned)(unsigned short)h) << 16);
}
__device__ __forceinline__ void split2(float v, short& hi, short& lo) {
  hi = f2bf(v);
  lo = f2bf(v - bf2f(hi));
}

// ---------------- block reduction helpers (256 threads, 4 waves) ----------------

__device__ __forceinline__ float2 block_sum2(float a, float b, float* sb) {
  #pragma unroll
  for (int o = 32; o; o >>= 1) { a += __shfl_down(a, o); b += __shfl_down(b, o); }
  const int lane = threadIdx.x & 63, wid = threadIdx.x >> 6;
  if (lane == 0) { sb[wid] = a; sb[4 + wid] = b; }
  __syncthreads();
  float ra = sb[0] + sb[1] + sb[2] + sb[3];
  float rb = sb[4] + sb[5] + sb[6] + sb[7];
  __syncthreads();
  return make_float2(ra, rb);
}

__device__ __forceinline__ float block_sum1(float a, float* sb) {
  #pragma unroll
  for (int o = 32; o; o >>= 1) a += __shfl_down(a, o);
  const int lane = threadIdx.x & 63, wid = threadIdx.x >> 6;
  if (lane == 0) sb[wid] = a;
  __syncthreads();
  float ra = sb[0] + sb[1] + sb[2] + sb[3];
  __syncthreads();
  return ra;
}

// ---------------- LayerNorm on x -> xn (split bf16 hi/lo) ----------------

__global__ __launch_bounds__(256) void ln1_kernel(
    const float* __restrict__ x, const float* __restrict__ w,
    const float* __restrict__ b, short* __restrict__ oh, short* __restrict__ ol) {
  __shared__ float sb[8];
  const size_t row = blockIdx.x;
  const int t = threadIdx.x;
  const float* xr = x + row * Dd;
  float2 xv = *(const float2*)(xr + 2 * t);
  float2 r = block_sum2(xv.x + xv.y, xv.x * xv.x + xv.y * xv.y, sb);
  const float mu = r.x * (1.f / Dd);
  const float var = r.y * (1.f / Dd) - mu * mu;
  const float rstd = rsqrtf(var + 1e-5f);
  float2 wv = *(const float2*)(w + 2 * t);
  float2 bv = *(const float2*)(b + 2 * t);
  float v0 = (xv.x - mu) * rstd * wv.x + bv.x;
  float v1 = (xv.y - mu) * rstd * wv.y + bv.y;
  short2 h2, l2;
  split2(v0, h2.x, l2.x);
  split2(v1, h2.y, l2.y);
  *(short2*)(oh + row * Dd + 2 * t) = h2;
  *(short2*)(ol + row * Dd + 2 * t) = l2;
}

// ------- LN2(attn_out)+residual -> h (f32) ; RMSNorm(h) -> zbf (bf16) -------

__global__ __launch_bounds__(256) void hz_kernel(
    const float* __restrict__ ao, const float* __restrict__ xres,
    const float* __restrict__ w, const float* __restrict__ b,
    const float* __restrict__ rw,
    float* __restrict__ h, short* __restrict__ zbf) {
  __shared__ float sb[8];
  const size_t row = blockIdx.x;
  const int t = threadIdx.x;
  float2 av = *(const float2*)(ao + row * Dd + 2 * t);
  float2 r = block_sum2(av.x + av.y, av.x * av.x + av.y * av.y, sb);
  const float mu = r.x * (1.f / Dd);
  const float var = r.y * (1.f / Dd) - mu * mu;
  const float rstd = rsqrtf(var + 1e-5f);
  float2 wv = *(const float2*)(w + 2 * t);
  float2 bv = *(const float2*)(b + 2 * t);
  float2 xv = *(const float2*)(xres + row * Dd + 2 * t);
  float2 hv;
  hv.x = (av.x - mu) * rstd * wv.x + bv.x + xv.x;
  hv.y = (av.y - mu) * rstd * wv.y + bv.y + xv.y;
  *(float2*)(h + row * Dd + 2 * t) = hv;
  float ms = block_sum1(hv.x * hv.x + hv.y * hv.y, sb) * (1.f / Dd);
  const float rr = rsqrtf(ms + 1.1920929e-07f);
  float2 rwv = *(const float2*)(rw + 2 * t);
  short2 zv;
  zv.x = f2bf(hv.x * rr * rwv.x);
  zv.y = f2bf(hv.y * rr * rwv.y);
  *(short2*)(zbf + row * Dd + 2 * t) = zv;
}

// ---------------- f32 -> bf16 converts ----------------

__global__ __launch_bounds__(256) void cvt_kernel(
    const float* __restrict__ in, short* __restrict__ out, int n4) {
  int i = blockIdx.x * 256 + threadIdx.x;
  if (i < n4) {
    float4 v = ((const float4*)in)[i];
    short4 o;
    o.x = f2bf(v.x); o.y = f2bf(v.y); o.z = f2bf(v.z); o.w = f2bf(v.w);
    ((short4*)out)[i] = o;
  }
}

__global__ __launch_bounds__(256) void cvt2_kernel(
    const float* __restrict__ in, short* __restrict__ hi,
    short* __restrict__ lo, int n4) {
  int i = blockIdx.x * 256 + threadIdx.x;
  if (i < n4) {
    float4 v = ((const float4*)in)[i];
    short4 h, l;
    split2(v.x, h.x, l.x); split2(v.y, h.y, l.y);
    split2(v.z, h.z, l.z); split2(v.w, h.w, l.w);
    ((short4*)hi)[i] = h;
    ((short4*)lo)[i] = l;
  }
}

// -------- V transpose: v[8192][512] bf16 -> vT[b][h][hd(64)][n(512)] bf16 --------

__global__ __launch_bounds__(256) void vt_kernel(
    const short* __restrict__ v, short* __restrict__ vT) {
  __shared__ short Lt[64][72];
  const int z = blockIdx.y, b = z >> 3, hh = z & 7;
  const int n0 = blockIdx.x * 64;
  const int tid = threadIdx.x;
  #pragma unroll
  for (int it = 0; it < 2; ++it) {
    int id = tid + it * 256;
    int r = id >> 3, c8 = id & 7;
    *(short8v*)&Lt[r][c8 * 8] =
        *(const short8v*)(v + ((size_t)(b * Nn + n0 + r)) * Dd + hh * HDd + c8 * 8);
  }
  __syncthreads();
  #pragma unroll
  for (int it = 0; it < 2; ++it) {
    int id = tid + it * 256;
    int c = id >> 3, r8 = id & 7;
    short8v g;
    #pragma unroll
    for (int k = 0; k < 8; ++k) g[k] = Lt[r8 * 8 + k][c];
    *(short8v*)(vT + ((size_t)z * HDd + c) * Nn + n0 + r8 * 8) = g;
  }
}

// ------ merged QKV 3-term split-bf16 NT GEMM ------

__global__ __launch_bounds__(256) void mfma_qkv3_kernel(
    const short* __restrict__ Ah, const short* __restrict__ Al,
    const short* __restrict__ Wh, const short* __restrict__ Wl,
    short* __restrict__ qh_, short* __restrict__ ql_,
    short* __restrict__ kh_, short* __restrict__ kl_,
    short* __restrict__ vh_) {
  constexpr int MREP = 4, NREP = 2;
  __shared__ short Ash[128][40], Asl[128][40], Bsh[64][40], Bsl[64][40];
  const int tid = threadIdx.x;
  const int wave = tid >> 6, lane = tid & 63;
  const int wr = wave >> 1, wc = wave & 1;
  const int lrow = lane & 15, kblk = lane >> 4;
  const size_t bm = (size_t)blockIdx.y * 128, bn = (size_t)blockIdx.x * 64;
  f32x4 acc[MREP][NREP] = {};
  for (int k0 = 0; k0 < Dd; k0 += 32) {
    __syncthreads();
    #pragma unroll
    for (int it = 0; it < 2; ++it) {
      int id = tid + it * 256;
      int r = id >> 2, kq = id & 3;
      const size_t go = (bm + r) * Dd + k0 + kq * 8;
      *(short8v*)&Ash[r][kq * 8] = *(const short8v*)(Ah + go);
      *(short8v*)&Asl[r][kq * 8] = *(const short8v*)(Al + go);
    }
    {
      int r = tid >> 2, kq = tid & 3;
      const size_t go = (bn + r) * Dd + k0 + kq * 8;
      *(short8v*)&Bsh[r][kq * 8] = *(const short8v*)(Wh + go);
      *(short8v*)&Bsl[r][kq * 8] = *(const short8v*)(Wl + go);
    }
    __syncthreads();
    short8v afh[MREP], afl[MREP], bfh[NREP], bfl[NREP];
    #pragma unroll
    for (int i = 0; i < MREP; ++i) {
      afh[i] = *(const short8v*)&Ash[wr * 64 + i * 16 + lrow][kblk * 8];
      afl[i] = *(const short8v*)&Asl[wr * 64 + i * 16 + lrow][kblk * 8];
    }
    #pragma unroll
    for (int j = 0; j < NREP; ++j) {
      bfh[j] = *(const short8v*)&Bsh[wc * 32 + j * 16 + lrow][kblk * 8];
      bfl[j] = *(const short8v*)&Bsl[wc * 32 + j * 16 + lrow][kblk * 8];
    }
    #pragma unroll
    for (int i = 0; i < MREP; ++i)
      #pragma unroll
      for (int j = 0; j < NREP; ++j) {
        acc[i][j] = __builtin_amdgcn_mfma_f32_16x16x32_bf16(afh[i], bfh[j], acc[i][j], 0, 0, 0);
        acc[i][j] = __builtin_amdgcn_mfma_f32_16x16x32_bf16(afl[i], bfh[j], acc[i][j], 0, 0, 0);
        acc[i][j] = __builtin_amdgcn_mfma_f32_16x16x32_bf16(afh[i], bfl[j], acc[i][j], 0, 0, 0);
      }
  }
  const int seg = (int)(bn >> 9);  // uniform per block
  short* dsth = seg == 0 ? qh_ : (seg == 1 ? kh_ : vh_);
  short* dstl = seg == 0 ? ql_ : kl_;
  #pragma unroll
  for (int i = 0; i < MREP; ++i) {
    #pragma unroll
    for (int j = 0; j < NREP; ++j) {
      const size_t gcol = (bn & 511) + wc * 32 + j * 16 + lrow;
      #pragma unroll
      for (int reg = 0; reg < 4; ++reg) {
        const size_t grow = bm + wr * 64 + i * 16 + kblk * 4 + reg;
        float vv = acc[i][j][reg];
        if (seg < 2) {
          short hh_, ll_;
          split2(vv, hh_, ll_);
          dsth[grow * Dd + gcol] = hh_;
          dstl[grow * Dd + gcol] = ll_;
        } else {
          dsth[grow * Dd + gcol] = f2bf(vv);
        }
      }
    }
  }
}

// ------ 3-term split-bf16 NT GEMM (out-proj): C = (Ah+Al)@(Wh+Wl)^T ------

template <int EPI>
__global__ __launch_bounds__(256) void mfma_nt3_kernel(
    const short* __restrict__ Ah, const short* __restrict__ Al,
    const short* __restrict__ Wh, const short* __restrict__ Wl,
    void* __restrict__ C1, void* __restrict__ C2,
    const float* __restrict__ bias, int Nc, int K) {
  constexpr int BM = 128, BN = 64;
  constexpr int MREP = 4, NREP = 2;
  __shared__ short Ash[BM][40], Asl[BM][40], Bsh[BN][40], Bsl[BN][40];
  const int tid = threadIdx.x;
  const int wave = tid >> 6, lane = tid & 63;
  const int wr = wave >> 1, wc = wave & 1;
  const int lrow = lane & 15, kblk = lane >> 4;
  const size_t bm = (size_t)blockIdx.y * BM, bn = (size_t)blockIdx.x * BN;
  f32x4 acc[MREP][NREP] = {};
  for (int k0 = 0; k0 < K; k0 += 32) {
    __syncthreads();
    #pragma unroll
    for (int it = 0; it < 2; ++it) {
      int id = tid + it * 256;
      int r = id >> 2, kq = id & 3;
      const size_t go = (bm + r) * K + k0 + kq * 8;
      *(short8v*)&Ash[r][kq * 8] = *(const short8v*)(Ah + go);
      *(short8v*)&Asl[r][kq * 8] = *(const short8v*)(Al + go);
    }
    {
      int r = tid >> 2, kq = tid & 3;
      const size_t go = (bn + r) * K + k0 + kq * 8;
      *(short8v*)&Bsh[r][kq * 8] = *(const short8v*)(Wh + go);
      *(short8v*)&Bsl[r][kq * 8] = *(const short8v*)(Wl + go);
    }
    __syncthreads();
    short8v afh[MREP], afl[MREP], bfh[NREP], bfl[NREP];
    #pragma unroll
    for (int i = 0; i < MREP; ++i) {
      afh[i] = *(const short8v*)&Ash[wr * 64 + i * 16 + lrow][kblk * 8];
      afl[i] = *(const short8v*)&Asl[wr * 64 + i * 16 + lrow][kblk * 8];
    }
    #pragma unroll
    for (int j = 0; j < NREP; ++j) {
      bfh[j] = *(const short8v*)&Bsh[wc * 32 + j * 16 + lrow][kblk * 8];
      bfl[j] = *(const short8v*)&Bsl[wc * 32 + j * 16 + lrow][kblk * 8];
    }
    #pragma unroll
    for (int i = 0; i < MREP; ++i)
      #pragma unroll
      for (int j = 0; j < NREP; ++j) {
        acc[i][j] = __builtin_amdgcn_mfma_f32_16x16x32_bf16(afh[i], bfh[j], acc[i][j], 0, 0, 0);
        acc[i][j] = __builtin_amdgcn_mfma_f32_16x16x32_bf16(afl[i], bfh[j], acc[i][j], 0, 0, 0);
        acc[i][j] = __builtin_amdgcn_mfma_f32_16x16x32_bf16(afh[i], bfl[j], acc[i][j], 0, 0, 0);
      }
  }
  #pragma unroll
  for (int i = 0; i < MREP; ++i) {
    #pragma unroll
    for (int j = 0; j < NREP; ++j) {
      const size_t gcol = bn + wc * 32 + j * 16 + lrow;
      float bb = 0.f;
      if constexpr (EPI == 1) bb = bias[gcol];
      #pragma unroll
      for (int reg = 0; reg < 4; ++reg) {
        const size_t grow = bm + wr * 64 + i * 16 + kblk * 4 + reg;
        float vv = acc[i][j][reg] + bb;
        if constexpr (EPI == 0) {
          short hh_, ll_;
          split2(vv, hh_, ll_);
          ((short*)C1)[grow * Nc + gcol] = hh_;
          ((short*)C2)[grow * Nc + gcol] = ll_;
        } else if constexpr (EPI == 1) {
          ((float*)C1)[grow * Nc + gcol] = vv;
        } else {
          ((short*)C1)[grow * Nc + gcol] = f2bf(vv);
        }
      }
    }
  }
}

// -------- fattn: fused scores (3-term) + u-bias + softmax + P write + P@V --------
// Flat 1-D grid, fid = h*256 + (b*16 + row_t): the 8 blocks sharing (b,row0)
// differ by 256 = 0 mod 8 -> same XCD (round-robin) -> u tile L2-hot across heads.

__global__ __launch_bounds__(256) void fattn_kernel(
    const short* __restrict__ qh, const short* __restrict__ ql,
    const short* __restrict__ kh, const short* __restrict__ kl,
    const short* __restrict__ vT, float* __restrict__ P,
    const float* __restrict__ u, const float* __restrict__ u_w,
    const float* __restrict__ u_b,
    short* __restrict__ ctxh, short* __restrict__ ctxl) {
  __shared__ __align__(16) char smem[50688];
  short (*Qsh)[72] = (short(*)[72])(smem + 0);
  short (*Qsl)[72] = (short(*)[72])(smem + 4608);
  short (*Ksh)[72] = (short(*)[72])(smem + 9216);
  short (*Ksl)[72] = (short(*)[72])(smem + 18432);
  float (*Sls)[68] = (float(*)[68])(smem + 27648);   // ends 36352
  short (*Ps)[520] = (short(*)[520])(smem + 0);      // phase C, ends 33280
  short (*Bs)[136] = (short(*)[136])(smem + 33280);  // phase C, ends 50688
  const int fid = blockIdx.x;
  const int h = fid >> 8;            // 0..7
  const int rb = fid & 255;          // b*16 + row_t
  const int b = rb >> 4;
  const int row0 = (rb & 15) * 32;
  const int z = (b << 3) | h;
  const int tid = threadIdx.x;
  const int lr = tid >> 3, sub = tid & 7;
  const int wave = tid >> 6, lane = tid & 63;
  const int wr = wave >> 1, wc = wave & 1;
  const int lrow = lane & 15, kblk = lane >> 4;

  // stage Q (32 rows x 64 k) hi/lo, once
  {
    const size_t gq = ((size_t)(b * Nn) + row0 + lr) * Dd + h * HDd + sub * 8;
    *(short8v*)&Qsh[lr][sub * 8] = *(const short8v*)(qh + gq);
    *(short8v*)&Qsl[lr][sub * 8] = *(const short8v*)(ql + gq);
  }
  float uw[UEe];
  #pragma unroll
  for (int c = 0; c < UEe; ++c) uw[c] = u_w[h * UEe + c];
  const float ubh = u_b[h];
  const float* ub_ = u + (size_t)b * UEe * Nn * Nn;

  float4 s[16];
  #pragma unroll
  for (int jt = 0; jt < 8; ++jt) {
    __syncthreads();  // Q visible (1st iter); prev pickup Sls-reads + MFMA Ks-reads done
    #pragma unroll
    for (int it = 0; it < 2; ++it) {
      int id = tid + it * 256;
      int r = id >> 3, kq = id & 7;
      const size_t gk = ((size_t)(b * Nn) + jt * 64 + r) * Dd + h * HDd + kq * 8;
      *(short8v*)&Ksh[r][kq * 8] = *(const short8v*)(kh + gk);
      *(short8v*)&Ksl[r][kq * 8] = *(const short8v*)(kl + gk);
    }
    __syncthreads();
    f32x4 acc[2] = {};
    #pragma unroll
    for (int ks = 0; ks < 2; ++ks) {
      short8v afh = *(const short8v*)&Qsh[wr * 16 + lrow][ks * 32 + kblk * 8];
      short8v afl = *(const short8v*)&Qsl[wr * 16 + lrow][ks * 32 + kblk * 8];
      #pragma unroll
      for (int j = 0; j < 2; ++j) {
        short8v bfh = *(const short8v*)&Ksh[wc * 32 + j * 16 + lrow][ks * 32 + kblk * 8];
        short8v bfl = *(const short8v*)&Ksl[wc * 32 + j * 16 + lrow][ks * 32 + kblk * 8];
        acc[j] = __builtin_amdgcn_mfma_f32_16x16x32_bf16(afh, bfh, acc[j], 0, 0, 0);
        acc[j] = __builtin_amdgcn_mfma_f32_16x16x32_bf16(afl, bfh, acc[j], 0, 0, 0);
        acc[j] = __builtin_amdgcn_mfma_f32_16x16x32_bf16(afh, bfl, acc[j], 0, 0, 0);
      }
    }
    // dump fragments -> Sls (scale by 8)
    #pragma unroll
    for (int j = 0; j < 2; ++j)
      #pragma unroll
      for (int reg = 0; reg < 4; ++reg)
        Sls[wr * 16 + kblk * 4 + reg][wc * 32 + j * 16 + lrow] = 8.f * acc[j][reg];
    __syncthreads();
    // pickup + u-bias into register layout
    #pragma unroll
    for (int dt = 0; dt < 2; ++dt) {
      const int t = jt * 2 + dt;
      float4 v = *(const float4*)&Sls[lr][dt * 32 + sub * 4];
      const size_t goff = (size_t)(row0 + lr) * Nn + 4 * (sub + 8 * t);
      v.x += ubh; v.y += ubh; v.z += ubh; v.w += ubh;
      #pragma unroll
      for (int c = 0; c < UEe; ++c) {
        float4 uv = *(const float4*)(ub_ + (size_t)c * Nn * Nn + goff);
        v.x = fmaf(uw[c], uv.x, v.x);
        v.y = fmaf(uw[c], uv.y, v.y);
        v.z = fmaf(uw[c], uv.z, v.z);
        v.w = fmaf(uw[c], uv.w, v.w);
      }
      s[t] = v;
    }
  }
  __syncthreads();  // all phase-A LDS reads done before Ps overlays

  // ---- softmax over s[16] (8-thread row groups, shfl over sub) ----
  float m = -1e30f;
  #pragma unroll
  for (int q = 0; q < 16; ++q)
    m = fmaxf(m, fmaxf(fmaxf(s[q].x, s[q].y), fmaxf(s[q].z, s[q].w)));
  m = fmaxf(m, __shfl_xor(m, 1));
  m = fmaxf(m, __shfl_xor(m, 2));
  m = fmaxf(m, __shfl_xor(m, 4));
  float sum = 0.f;
  #pragma unroll
  for (int q = 0; q < 16; ++q) {
    s[q].x = __expf(s[q].x - m); s[q].y = __expf(s[q].y - m);
    s[q].z = __expf(s[q].z - m); s[q].w = __expf(s[q].w - m);
    sum += (s[q].x + s[q].y) + (s[q].z + s[q].w);
  }
  sum += __shfl_xor(sum, 1);
  sum += __shfl_xor(sum, 2);
  sum += __shfl_xor(sum, 4);
  const float rr = 1.f / sum;
  // ---- P write (f32) + Ps pack (bf16) ----
  float* Pp = P + (size_t)z * Nn * Nn + (size_t)(row0 + lr) * Nn;
  #pragma unroll
  for (int q = 0; q < 16; ++q) {
    s[q].x *= rr; s[q].y *= rr; s[q].z *= rr; s[q].w *= rr;
    const int col = 4 * (sub + 8 * q);
    *(float4*)(Pp + col) = s[q];
    short4 pk;
    pk.x = f2bf(s[q].x); pk.y = f2bf(s[q].y);
    pk.z = f2bf(s[q].z); pk.w = f2bf(s[q].w);
    *(short4*)&Ps[lr][col] = pk;
  }
  // ---- PV MFMA: ctx_tile[32][64] = P_tile[32][512] @ V[512][64] ----
  f32x4 acc0 = {}, acc1 = {};
  for (int kc = 0; kc < 4; ++kc) {
    __syncthreads();  // (1st iter: Ps writes visible; later: prev MFMA Bs reads done)
    #pragma unroll
    for (int it = 0; it < 4; ++it) {
      int id = tid + it * 256;
      int rrow = id >> 4, k8 = id & 15;
      *(short8v*)&Bs[rrow][k8 * 8] =
          *(const short8v*)(vT + ((size_t)z * HDd + rrow) * Nn + kc * 128 + k8 * 8);
    }
    __syncthreads();
    #pragma unroll
    for (int ks = 0; ks < 4; ++ks) {
      short8v af = *(const short8v*)&Ps[wr * 16 + lrow][kc * 128 + ks * 32 + kblk * 8];
      short8v b0 = *(const short8v*)&Bs[wc * 32 + lrow][ks * 32 + kblk * 8];
      short8v b1 = *(const short8v*)&Bs[wc * 32 + 16 + lrow][ks * 32 + kblk * 8];
      acc0 = __builtin_amdgcn_mfma_f32_16x16x32_bf16(af, b0, acc0, 0, 0, 0);
      acc1 = __builtin_amdgcn_mfma_f32_16x16x32_bf16(af, b1, acc1, 0, 0, 0);
    }
  }
  const size_t outbase =
      ((size_t)(b * Nn + row0 + wr * 16 + kblk * 4)) * Dd + h * HDd + wc * 32 + lrow;
  #pragma unroll
  for (int reg = 0; reg < 4; ++reg) {
    short h0, l0, h1, l1;
    split2(acc0[reg], h0, l0);
    split2(acc1[reg], h1, l1);
    ctxh[outbase + (size_t)reg * Dd] = h0;
    ctxl[outbase + (size_t)reg * Dd] = l0;
    ctxh[outbase + (size_t)reg * Dd + 16] = h1;
    ctxl[outbase + (size_t)reg * Dd + 16] = l1;
  }
}

// ---------------- bf16 MFMA NT GEMM (FFN) ----------------

template <int BM, int BN, int EPI>
__global__ __launch_bounds__(256) void mfma_nt_kernel(
    const short* __restrict__ Ag, const short* __restrict__ Wg,
    void* __restrict__ Cv, const float* __restrict__ bias,
    const float* __restrict__ res, int Nc, int K) {
  constexpr int MREP = BM / 32, NREP = BN / 32;
  __shared__ short As[BM][72];
  __shared__ short Bs[BN][72];
  const int tid = threadIdx.x;
  const int wave = tid >> 6, lane = tid & 63;
  const int wr = wave >> 1, wc = wave & 1;
  const int lrow = lane & 15, kblk = lane >> 4;
  const size_t bm = (size_t)blockIdx.y * BM, bn = (size_t)blockIdx.x * BN;
  f32x4 acc[MREP][NREP] = {};
  for (int k0 = 0; k0 < K; k0 += 32) {
    __syncthreads();
    #pragma unroll
    for (int it = 0; it < BM / 64; ++it) {
      int id = tid + it * 256;
      int r = id >> 2, kq = id & 3;
      *(short8v*)&As[r][kq * 8] = *(const short8v*)(Ag + (bm + r) * K + k0 + kq * 8);
    }
    #pragma unroll
    for (int it = 0; it < BN / 64; ++it) {
      int id = tid + it * 256;
      int r = id >> 2, kq = id & 3;
      *(short8v*)&Bs[r][kq * 8] = *(const short8v*)(Wg + (bn + r) * K + k0 + kq * 8);
    }
    __syncthreads();
    short8v af[MREP], bf[NREP];
    #pragma unroll
    for (int i = 0; i < MREP; ++i)
      af[i] = *(const short8v*)&As[wr * (BM / 2) + i * 16 + lrow][kblk * 8];
    #pragma unroll
    for (int j = 0; j < NREP; ++j)
      bf[j] = *(const short8v*)&Bs[wc * (BN / 2) + j * 16 + lrow][kblk * 8];
    #pragma unroll
    for (int i = 0; i < MREP; ++i)
      #pragma unroll
      for (int j = 0; j < NREP; ++j)
        acc[i][j] = __builtin_amdgcn_mfma_f32_16x16x32_bf16(af[i], bf[j], acc[i][j], 0, 0, 0);
  }
  #pragma unroll
  for (int i = 0; i < MREP; ++i) {
    #pragma unroll
    for (int j = 0; j < NREP; ++j) {
      const size_t gcol = bn + wc * (BN / 2) + j * 16 + lrow;
      const float bb = bias[gcol];
      #pragma unroll
      for (int reg = 0; reg < 4; ++reg) {
        const size_t grow = bm + wr * (BM / 2) + i * 16 + kblk * 4 + reg;
        float vv = acc[i][j][reg] + bb;
        if constexpr (EPI == 0) {
          vv = vv / (1.f + __expf(-vv));
          ((short*)Cv)[grow * Nc + gcol] = f2bf(vv);
        } else {
          ((float*)Cv)[grow * Nc + gcol] = vv + res[grow * Nc + gcol];
        }
      }
    }
  }
}

// ---------------- host launch ----------------

extern "C" void kernel_launch(void* const* d_in, const int* in_sizes, int n_in,
                              void* d_out, int out_size, void* d_ws, size_t ws_size,
                              hipStream_t stream) {
  const float* x     = (const float*)d_in[0];
  const float* u     = (const float*)d_in[1];
  const float* ln1_w = (const float*)d_in[2];
  const float* ln1_b = (const float*)d_in[3];
  const float* ln2_w = (const float*)d_in[4];
  const float* ln2_b = (const float*)d_in[5];
  const float* wq    = (const float*)d_in[6];
  const float* wk    = (const float*)d_in[7];
  const float* wv    = (const float*)d_in[8];
  const float* wo    = (const float*)d_in[9];
  const float* bo    = (const float*)d_in[10];
  const float* u_w   = (const float*)d_in[11];
  const float* u_b   = (const float*)d_in[12];
  const float* rms_w = (const float*)d_in[13];
  const float* w1    = (const float*)d_in[14];
  const float* b1    = (const float*)d_in[15];
  const float* w2    = (const float*)d_in[16];
  const float* b2    = (const float*)d_in[17];

  float* out   = (float*)d_out;
  float* attnW = out + (size_t)Bb * Nn * Dd;  // second output: [B,H,N,N]

  const size_t SB = (size_t)Bb * Nn * Dd * 2;  // 8 MB
  char* wsb = (char*)d_ws;
  // slot map (8 MB each):
  // 0: xnh -> vTh -> zbf     | 1: xnl -> ctxh -> h1bf[0:8]
  // 2: qh  -> aout[0:8]      | 3: ql -> aout[8:16]   (h1bf[8:24] after hz)
  // 4: kh  -> h1bf[24:32]    | 5: kl -> hbuf[0:8]
  // 6: vh  -> ctxl -> hbuf[8:16]
  short* xnh  = (short*)(wsb + 0 * SB);
  short* xnl  = (short*)(wsb + 1 * SB);
  short* qh   = (short*)(wsb + 2 * SB);
  short* ql   = (short*)(wsb + 3 * SB);
  short* kh   = (short*)(wsb + 4 * SB);
  short* kl   = (short*)(wsb + 5 * SB);
  short* vh   = (short*)(wsb + 6 * SB);
  short* vTh  = (short*)(wsb + 0 * SB);
  short* ctxh = (short*)(wsb + 1 * SB);
  short* ctxl = (short*)(wsb + 6 * SB);
  float* aout = (float*)(wsb + 2 * SB);
  float* hbuf = (float*)(wsb + 5 * SB);
  short* zbf  = (short*)(wsb + 0 * SB);
  short* h1bf = (short*)(wsb + 1 * SB);  // 32 MB: slots 1-4
  const size_t WTBYTES = 8 * (size_t)Dd * Dd * 2 + 2 * (size_t)DFFf * Dd * 2;
  const size_t wt = (ws_size - WTBYTES) & ~(size_t)255;
  short* wAh = (short*)(wsb + wt);
  short* wAl = wAh + 3 * (size_t)Dd * Dd;
  short* woh = wAl + 3 * (size_t)Dd * Dd;
  short* wol = woh + (size_t)Dd * Dd;
  short* w1h = wol + (size_t)Dd * Dd;
  short* w2h = w1h + (size_t)DFFf * Dd;

  const int MR = Bb * Nn;  // 8192 rows

  // 0. weight converts
  cvt2_kernel<<<256, 256, 0, stream>>>(wq, wAh, wAl, Dd * Dd / 4);
  cvt2_kernel<<<256, 256, 0, stream>>>(wk, wAh + (size_t)Dd * Dd, wAl + (size_t)Dd * Dd, Dd * Dd / 4);
  cvt2_kernel<<<256, 256, 0, stream>>>(wv, wAh + 2 * (size_t)Dd * Dd, wAl + 2 * (size_t)Dd * Dd, Dd * Dd / 4);
  cvt2_kernel<<<256, 256, 0, stream>>>(wo, woh, wol, Dd * Dd / 4);
  cvt_kernel<<<1024, 256, 0, stream>>>(w1, w1h, DFFf * Dd / 4);
  cvt_kernel<<<1024, 256, 0, stream>>>(w2, w2h, DFFf * Dd / 4);

  // 1. LayerNorm1 -> split bf16
  ln1_kernel<<<MR, 256, 0, stream>>>(x, ln1_w, ln1_b, xnh, xnl);

  // 2. merged Q,K,V projection (3-term split MFMA)
  dim3 gQKV(3 * Dd / 64, MR / 128);
  mfma_qkv3_kernel<<<gQKV,256,0,stream>>>(xnh, xnl, wAh, wAl, qh, ql, kh, kl, vh);

  // 3. V transpose per head
  dim3 gVt(Nn / 64, Bb * Hh);
  vt_kernel<<<gVt, 256, 0, stream>>>(vh, vTh);

  // 4. fused scores + u-bias + softmax + P + P@V (XCD-aware flat grid)
  fattn_kernel<<<Hh * Bb * (Nn / 32), 256, 0, stream>>>(
      qh, ql, kh, kl, vTh, attnW, u, u_w, u_b, ctxh, ctxl);

  // 5. attn_out = ctx @ wo^T + bo (3-term, f32 out)
  dim3 gProj(Dd / 64, MR / 128);
  mfma_nt3_kernel<1><<<gProj,256,0,stream>>>(ctxh, ctxl, woh, wol, aout, nullptr, bo, Dd, Dd);

  // 6. h = LN2(attn_out) + x ; zbf = bf16(RMSNorm(h))
  hz_kernel<<<MR, 256, 0, stream>>>(aout, x, ln2_w, ln2_b, rms_w, hbuf, zbf);

  // 7/8. FFN bf16 MFMA, single pass (h1bf = 32 MB, slots 1-4)
  dim3 gF1(DFFf / 128, MR / 128);
  mfma_nt_kernel<128,128,0><<<gF1,256,0,stream>>>(
      zbf, w1h, h1bf, b1, nullptr, DFFf, Dd);
  dim3 gF2(Dd / 128, MR / 64);
  mfma_nt_kernel<64,128,1><<<gF2,256,0,stream>>>(
      h1bf, w2h, out, b2, hbuf, Dd, DFFf);
}